// Round 6
// baseline (138.024 us; speedup 1.0000x reference)
//
#include <hip/hip_runtime.h>

#define BATCH 65536
#define NSPL  64
#define CDIM  64
#define TDIM  68          // CDIM + DEGREE + 1
#define QI    67          // degree-0 intervals

#define TCOLS 16          // splines per block: full 64B line per row (no write amp)
#define TROWS 512         // rows per block
#define NWAVE 8
#define NTHR  (NWAVE * 64)
#define RPT   8           // rows per lane per column (one table read feeds 8 rows)
#define PITCH 513         // 513 % 32 == 1: compute phase stride-1 free, staging <=4-way

typedef float v2f __attribute__((ext_vector_type(2)));

static __device__ __forceinline__ v2f splat2(float f) { v2f v; v.x = f; v.y = f; return v; }
static __device__ __forceinline__ v2f fma2(v2f a, v2f b, v2f c) {
#if __has_builtin(__builtin_elementwise_fma)
    return __builtin_elementwise_fma(a, b, c);
#else
    v2f r; r.x = fmaf(a.x, b.x, c.x); r.y = fmaf(a.y, b.y, c.y); return r;
#endif
}

// ============================================================================
// S(x) = sum_i [t_i <= x < t_{i+1}] * Q_i(x); Q_i cubic in x (<=8 Cox-de Boor
// lattice paths, fp64 expansion).
// Round-5 lessons: (a) scalar s_load table stream stalls all waves in phase
// (340 dwords/column through ~80 SGPRs; sK$ 16KB << 68KB working set) -> feed
// tables from LDS via wave-uniform broadcast ds_read_b128, prefetched on the
// VGPR budget with fine-grained lgkmcnt; (b) 32B row segments re-amplified
// writes (24->40MB) -> back to 16-spline tiles = full 64B lines; (c) the
// separate build_q dispatch cost ~20us of bench wall -> fused into this
// kernel as a ~2us cooperative per-block phase (d_ws now unused).
// ============================================================================
__global__ __launch_bounds__(NTHR) void bspline_fused(
    const float* __restrict__ X,   // [BATCH, NSPL]
    const float* __restrict__ T,   // [NSPL, TDIM]
    const float* __restrict__ C,   // [NSPL, CDIM]
    float* __restrict__ O)         // [BATCH, NSPL]
{
    __shared__ float4 tq[TCOLS * QI];     // 17152 B: cubic coeffs per (col, interval)
    __shared__ float  tk[TCOLS * TDIM];   //  4352 B: knots per col
    __shared__ float  xl[TCOLS * PITCH];  // 32832 B: x tile [col][row]; reused for out

    const int tid  = threadIdx.x;
    const int lane = tid & 63;
    const int w    = tid >> 6;
    const int r0   = blockIdx.x * TROWS;
    const int s0   = blockIdx.y * TCOLS;

    // ---- Phase A: knots -> LDS (flat coalesced copy) ----
    for (int e = tid; e < TCOLS * TDIM; e += NTHR)
        tk[e] = T[s0 * TDIM + e];
    __syncthreads();

    // ---- Phase B: fp64 safe-reciprocal tables, built in a union over xl ----
    // Per col: R1[67] | R2[66](at +67) | R3[65](at +133); 198 doubles/col.
    // fl64(a)-fl64(b) == 0 iff fp32 a==b -> matches reference 0/0 := 0.
    double* Rbuf = (double*)xl;           // 16*198*8 = 25344 B <= 32832 B
    for (int e = tid; e < TCOLS * 198; e += NTHR) {
        int c = e / 198, r = e - c * 198;
        const float* kn = tk + c * TDIM;
        double d;
        if (r < 67)       { d = (double)kn[r + 1] - (double)kn[r]; }
        else if (r < 133) { int i = r - 67;  d = (double)kn[i + 2] - (double)kn[i]; }
        else              { int i = r - 133; d = (double)kn[i + 3] - (double)kn[i]; }
        Rbuf[e] = (d == 0.0) ? 0.0 : 1.0 / d;
    }
    __syncthreads();

    // ---- Phase C: expand Q_i (fp64 path sum; ~2-3 (col,interval) pairs/thread) ----
    for (int e = tid; e < TCOLS * QI; e += NTHR) {
        int c = e / QI, i = e - c * QI;
        const float*  kn = tk + c * TDIM;
        const double* R1 = Rbuf + c * 198;
        const double* R2 = R1 + 67;
        const double* R3 = R1 + 133;
        const float*  cg = C + (s0 + c) * CDIM;   // L2-hot, tiny
        double q0 = 0, q1 = 0, q2 = 0, q3 = 0;
        for (int j = i - 3; j <= i; ++j) {
            if (j < 0 || j > CDIM - 1) continue;
            double cj = (double)cg[j];
            for (int b2 = 0; b2 < 2; ++b2) {
                int m2 = j + b2;
                double D3 = R3[j + b2];
                double p3 = b2 ? -D3 : D3;
                double r3 = b2 ? D3 * (double)kn[j + 4] : -D3 * (double)kn[j];
                for (int b1 = 0; b1 < 2; ++b1) {
                    int m1 = m2 + b1;
                    double D2 = R2[m2 + b1];
                    double p2 = b1 ? -D2 : D2;
                    double r2 = b1 ? D2 * (double)kn[m2 + 3] : -D2 * (double)kn[m2];
                    for (int b0 = 0; b0 < 2; ++b0) {
                        if (m1 + b0 != i) continue;  // path must end at interval i
                        double D1 = R1[m1 + b0];
                        double p1 = b0 ? -D1 : D1;
                        double r1 = b0 ? D1 * (double)kn[m1 + 2] : -D1 * (double)kn[m1];
                        double a2 = p3 * p2, a1 = p3 * r2 + r3 * p2, a0 = r3 * r2;
                        q3 += cj * (a2 * p1);
                        q2 += cj * (a2 * r1 + a1 * p1);
                        q1 += cj * (a1 * r1 + a0 * p1);
                        q0 += cj * (a0 * r1);
                    }
                }
            }
        }
        float4 v; v.x = (float)q0; v.y = (float)q1; v.z = (float)q2; v.w = (float)q3;
        tq[e] = v;
    }
    __syncthreads();   // Rbuf (aliasing xl) fully consumed

    // ---- Phase D: stage X tile (coalesced: 4 full 64B lines per wave-instr) ----
    #pragma unroll
    for (int it = 0; it < TROWS * TCOLS / NTHR; ++it) {   // 16 iters
        int e = tid + it * NTHR;
        int r = e >> 4, c = e & 15;
        xl[c * PITCH + r] = X[(r0 + r) * NSPL + s0 + c];
    }
    __syncthreads();

    // ---- Phase E: compute; wave w owns columns 2w, 2w+1 ----
    #pragma unroll 1
    for (int cc = 0; cc < 2; ++cc) {
        const int c = w * 2 + cc;
        const float4* q  = tq + c * QI;      // wave-uniform ds_read_b128 broadcast
        const float*  kn = tk + c * TDIM;    // wave-uniform ds_read_b32 broadcast
        float* xc = xl + c * PITCH + lane;

        v2f xx[4], aa[4];
        #pragma unroll
        for (int p = 0; p < 4; ++p) {
            xx[p].x = xc[128 * p];           // stride-1 rows: conflict-free
            xx[p].y = xc[128 * p + 64];
            aa[p] = splat2(0.f);
        }
        bool ge[RPT];
        {
            float t0 = kn[0];
            #pragma unroll
            for (int p = 0; p < 4; ++p) {
                ge[2 * p]     = (xx[p].x >= t0);
                ge[2 * p + 1] = (xx[p].y >= t0);
            }
        }
        #pragma unroll
        for (int i = 0; i < QI; ++i) {
            float4 qq = q[i];
            float  tn = kn[i + 1];
            v2f qw = splat2(qq.w), qz = splat2(qq.z), qy = splat2(qq.y), qx = splat2(qq.x);
            #pragma unroll
            for (int p = 0; p < 4; ++p) {
                v2f poly = fma2(fma2(fma2(qw, xx[p], qz), xx[p], qy), xx[p], qx);
                bool n0 = (xx[p].x >= tn), n1 = (xx[p].y >= tn);
                v2f sel;
                sel.x = (ge[2 * p]     && !n0) ? poly.x : 0.f;
                sel.y = (ge[2 * p + 1] && !n1) ? poly.y : 0.f;
                aa[p] += sel;                 // v_pk_add_f32
                ge[2 * p] = n0; ge[2 * p + 1] = n1;
            }
        }
        // In-place write-back: column c touched only by wave w; all x reads for
        // this column happened above in wave lockstep -> no barrier needed.
        #pragma unroll
        for (int p = 0; p < 4; ++p) {
            xc[128 * p]      = aa[p].x;
            xc[128 * p + 64] = aa[p].y;
        }
    }
    __syncthreads();

    // ---- Phase F: write out (full 64B lines; LDS read <=4-way on staging pattern) ----
    #pragma unroll
    for (int it = 0; it < TROWS * TCOLS / NTHR; ++it) {
        int e = tid + it * NTHR;
        int r = e >> 4, c = e & 15;
        O[(r0 + r) * NSPL + s0 + c] = xl[c * PITCH + r];
    }
}

extern "C" void kernel_launch(void* const* d_in, const int* in_sizes, int n_in,
                              void* d_out, int out_size, void* d_ws, size_t ws_size,
                              hipStream_t stream) {
    const float* X = (const float*)d_in[0];  // [65536, 64]
    const float* T = (const float*)d_in[1];  // [64, 68]
    const float* C = (const float*)d_in[2];  // [64, 64]
    float* O = (float*)d_out;                // [65536, 64]

    dim3 grid(BATCH / TROWS, NSPL / TCOLS);  // (128, 4) = 512 blocks, 2/CU resident
    bspline_fused<<<grid, NTHR, 0, stream>>>(X, T, C, O);
}

// Round 7
// 132.457 us; speedup vs baseline: 1.0420x; 1.0420x over previous
//
#include <hip/hip_runtime.h>

#define BATCH 65536
#define NSPL  64
#define CDIM  64
#define TDIM  68          // CDIM + DEGREE + 1
#define QI    67          // degree-0 intervals

#define TCOLS 16          // splines per block: full 64B line per row (no write amp)
#define TROWS 512         // rows per block
#define NWAVE 8
#define NTHR  (NWAVE * 64)
#define PITCH 513         // 513 % 32 == 1: compute stride-1 free, staging <=4-way

typedef float v2f __attribute__((ext_vector_type(2)));

static __device__ __forceinline__ v2f splat2(float f) { v2f v; v.x = f; v.y = f; return v; }
static __device__ __forceinline__ v2f fma2(v2f a, v2f b, v2f c) {
#if __has_builtin(__builtin_elementwise_fma)
    return __builtin_elementwise_fma(a, b, c);
#else
    v2f r; r.x = fmaf(a.x, b.x, c.x); r.y = fmaf(a.y, b.y, c.y); return r;
#endif
}
// Wave-uniform broadcast from a lane-resident table: pure VALU, no memory pipe.
static __device__ __forceinline__ float rdlane(float v, int l) {
    return __builtin_bit_cast(float, __builtin_amdgcn_readlane(__builtin_bit_cast(int, v), l));
}

// One interval step for 8 rows (4 packed pairs). qx..qw, tn are wave-uniform.
static __device__ __forceinline__ void step8(float qx, float qy, float qz, float qw,
                                             float tn, v2f xx[4], v2f aa[4], bool ge[8]) {
    v2f vqw = splat2(qw), vqz = splat2(qz), vqy = splat2(qy), vqx = splat2(qx);
    #pragma unroll
    for (int p = 0; p < 4; ++p) {
        v2f poly = fma2(vqw, xx[p], vqz);
        poly = fma2(poly, xx[p], vqy);
        poly = fma2(poly, xx[p], vqx);
        bool n0 = (xx[p].x >= tn), n1 = (xx[p].y >= tn);
        v2f sel;
        sel.x = (ge[2 * p]     && !n0) ? poly.x : 0.f;   // ind = ge_i && !ge_{i+1}
        sel.y = (ge[2 * p + 1] && !n1) ? poly.y : 0.f;
        aa[p] += sel;
        ge[2 * p] = n0; ge[2 * p + 1] = n1;
    }
}

// ============================================================================
// S(x) = sum_i [t_i <= x < t_{i+1}] * Q_i(x); Q_i cubic in x (<=8 Cox-de Boor
// lattice paths, fp64 expansion, built cooperatively per block).
// Round-6 lesson: in-loop LDS table reads serialize (load->lgkmcnt->use at
// VGPR=44, not enough waves to hide ~120cyc LDS latency) and the 2x67
// fully-unrolled body overflowed I-cache. Round-7: per-column tables live in
// 10 lane-indexed VGPRs (lane = interval); the wave-uniform interval loop
// broadcasts 5 scalars/interval via v_readlane (VALU, zero latency). Inner
// loop is rolled (unroll 4, ~1.3KB code) and touches NO memory pipe.
// ============================================================================
__global__ __launch_bounds__(NTHR) void bspline_fused(
    const float* __restrict__ X,   // [BATCH, NSPL]
    const float* __restrict__ T,   // [NSPL, TDIM]
    const float* __restrict__ C,   // [NSPL, CDIM]
    float* __restrict__ O)         // [BATCH, NSPL]
{
    __shared__ float4 tq[TCOLS * QI];     // 17152 B: cubic coeffs per (col, interval)
    __shared__ float  tk[TCOLS * TDIM];   //  4352 B: knots per col
    __shared__ float  xl[TCOLS * PITCH];  // 32832 B: x tile [col][row]; reused for out

    const int tid  = threadIdx.x;
    const int lane = tid & 63;
    const int w    = tid >> 6;
    const int r0   = blockIdx.x * TROWS;
    const int s0   = blockIdx.y * TCOLS;

    // ---- Phase A: knots -> LDS (flat coalesced copy) ----
    for (int e = tid; e < TCOLS * TDIM; e += NTHR)
        tk[e] = T[s0 * TDIM + e];
    __syncthreads();

    // ---- Phase B: fp64 safe-reciprocal tables, built in a union over xl ----
    // Per col: R1[67] | R2[66](+67) | R3[65](+133); 198 doubles/col.
    // fl64(a)-fl64(b) == 0 iff fp32 a==b -> matches reference 0/0 := 0.
    double* Rbuf = (double*)xl;           // 16*198*8 = 25344 B <= 32832 B
    for (int e = tid; e < TCOLS * 198; e += NTHR) {
        int c = e / 198, r = e - c * 198;
        const float* kn = tk + c * TDIM;
        double d;
        if (r < 67)       { d = (double)kn[r + 1] - (double)kn[r]; }
        else if (r < 133) { int i = r - 67;  d = (double)kn[i + 2] - (double)kn[i]; }
        else              { int i = r - 133; d = (double)kn[i + 3] - (double)kn[i]; }
        Rbuf[e] = (d == 0.0) ? 0.0 : 1.0 / d;
    }
    __syncthreads();

    // ---- Phase C: expand Q_i (fp64 path sum; ~2 (col,interval) pairs/thread) ----
    for (int e = tid; e < TCOLS * QI; e += NTHR) {
        int c = e / QI, i = e - c * QI;
        const float*  kn = tk + c * TDIM;
        const double* R1 = Rbuf + c * 198;
        const double* R2 = R1 + 67;
        const double* R3 = R1 + 133;
        const float*  cg = C + (s0 + c) * CDIM;   // tiny, L2-hot
        double q0 = 0, q1 = 0, q2 = 0, q3 = 0;
        for (int j = i - 3; j <= i; ++j) {
            if (j < 0 || j > CDIM - 1) continue;
            double cj = (double)cg[j];
            for (int b2 = 0; b2 < 2; ++b2) {
                int m2 = j + b2;
                double D3 = R3[j + b2];
                double p3 = b2 ? -D3 : D3;
                double r3 = b2 ? D3 * (double)kn[j + 4] : -D3 * (double)kn[j];
                for (int b1 = 0; b1 < 2; ++b1) {
                    int m1 = m2 + b1;
                    double D2 = R2[m2 + b1];
                    double p2 = b1 ? -D2 : D2;
                    double r2 = b1 ? D2 * (double)kn[m2 + 3] : -D2 * (double)kn[m2];
                    for (int b0 = 0; b0 < 2; ++b0) {
                        if (m1 + b0 != i) continue;  // path must end at interval i
                        double D1 = R1[m1 + b0];
                        double p1 = b0 ? -D1 : D1;
                        double r1 = b0 ? D1 * (double)kn[m1 + 2] : -D1 * (double)kn[m1];
                        double a2 = p3 * p2, a1 = p3 * r2 + r3 * p2, a0 = r3 * r2;
                        q3 += cj * (a2 * p1);
                        q2 += cj * (a2 * r1 + a1 * p1);
                        q1 += cj * (a1 * r1 + a0 * p1);
                        q0 += cj * (a0 * r1);
                    }
                }
            }
        }
        float4 v; v.x = (float)q0; v.y = (float)q1; v.z = (float)q2; v.w = (float)q3;
        tq[e] = v;
    }
    __syncthreads();   // Rbuf (aliasing xl) fully consumed

    // ---- Phase D: stage X tile (coalesced: 4 full 64B lines per wave-instr) ----
    #pragma unroll
    for (int it = 0; it < TROWS * TCOLS / NTHR; ++it) {   // 16 iters
        int e = tid + it * NTHR;
        int r = e >> 4, c = e & 15;
        xl[c * PITCH + r] = X[(r0 + r) * NSPL + s0 + c];
    }
    __syncthreads();

    // ---- Phase E: compute; wave w owns columns 2w, 2w+1 ----
    #pragma unroll 1
    for (int cc = 0; cc < 2; ++cc) {
        const int c = w * 2 + cc;

        // Lane-resident tables: lane i holds interval i / knot i+1. 10 VGPRs.
        const float4 qA = tq[c * QI + lane];                              // intervals 0..63
        const float4 qB = tq[c * QI + 64 + (lane < 3 ? lane : 2)];        // intervals 64..66
        const float  ktS = tk[c * TDIM + 1 + lane];                       // knots 1..64
        const float  ktT = tk[c * TDIM + 65 + (lane < 3 ? lane : 2)];     // knots 65..67
        const float  kt0 = tk[c * TDIM];                                  // knot 0 (uniform)

        float* xc = xl + c * PITCH + lane;
        v2f xx[4], aa[4];
        bool ge[8];
        #pragma unroll
        for (int p = 0; p < 4; ++p) {
            xx[p].x = xc[128 * p];           // stride-1 rows: conflict-free
            xx[p].y = xc[128 * p + 64];
            aa[p] = splat2(0.f);
            ge[2 * p]     = (xx[p].x >= kt0);
            ge[2 * p + 1] = (xx[p].y >= kt0);
        }

        // Rolled interval loop: 5 readlane broadcasts + 32 VALU per step,
        // ZERO memory ops. Knot i+1 lives at ktS lane i.
        #pragma unroll 4
        for (int i = 0; i < 64; ++i) {
            step8(rdlane(qA.x, i), rdlane(qA.y, i), rdlane(qA.z, i), rdlane(qA.w, i),
                  rdlane(ktS, i), xx, aa, ge);
        }
        // Tail intervals 64..66 (knots 65..67 at ktT lanes 0..2).
        step8(rdlane(qB.x, 0), rdlane(qB.y, 0), rdlane(qB.z, 0), rdlane(qB.w, 0),
              rdlane(ktT, 0), xx, aa, ge);
        step8(rdlane(qB.x, 1), rdlane(qB.y, 1), rdlane(qB.z, 1), rdlane(qB.w, 1),
              rdlane(ktT, 1), xx, aa, ge);
        step8(rdlane(qB.x, 2), rdlane(qB.y, 2), rdlane(qB.z, 2), rdlane(qB.w, 2),
              rdlane(ktT, 2), xx, aa, ge);

        // In-place write-back: column c touched only by wave w; all x reads for
        // this column happened above in wave lockstep -> no barrier needed.
        #pragma unroll
        for (int p = 0; p < 4; ++p) {
            xc[128 * p]      = aa[p].x;
            xc[128 * p + 64] = aa[p].y;
        }
    }
    __syncthreads();

    // ---- Phase F: write out (full 64B lines per row) ----
    #pragma unroll
    for (int it = 0; it < TROWS * TCOLS / NTHR; ++it) {
        int e = tid + it * NTHR;
        int r = e >> 4, c = e & 15;
        O[(r0 + r) * NSPL + s0 + c] = xl[c * PITCH + r];
    }
}

extern "C" void kernel_launch(void* const* d_in, const int* in_sizes, int n_in,
                              void* d_out, int out_size, void* d_ws, size_t ws_size,
                              hipStream_t stream) {
    const float* X = (const float*)d_in[0];  // [65536, 64]
    const float* T = (const float*)d_in[1];  // [64, 68]
    const float* C = (const float*)d_in[2];  // [64, 64]
    float* O = (float*)d_out;                // [65536, 64]

    dim3 grid(BATCH / TROWS, NSPL / TCOLS);  // (128, 4) = 512 blocks, 2/CU resident
    bspline_fused<<<grid, NTHR, 0, stream>>>(X, T, C, O);
}

// Round 8
// 102.166 us; speedup vs baseline: 1.3510x; 1.2965x over previous
//
#include <hip/hip_runtime.h>

#define BATCH 65536
#define NSPL  64
#define CDIM  64
#define TDIM  68          // CDIM + DEGREE + 1
#define QI    67          // degree-0 intervals
#define RTN   67          // region-table entries per spline (region idx m = 1..67)

#define TCOLS 16          // splines per block: full 64B line per row
#define TROWS 128         // rows per block
#define NTHR  256
#define PITCH 129         // 129 % 32 == 1: transposed access bank-stride 1

// ============================================================================
// Sorted-region reformulation. S(x) = sum_i [t_i<=x<t_{i+1}] Q_i(x) is
// piecewise-CUBIC in x with breakpoints exactly at the sorted knot values:
// the active set {i: t_i<=x<t_{i+1}} is constant between consecutive sorted
// knots. Prep (one block/spline): expand Q_i (fp64, <=8 lattice paths),
// rank-sort knots, and for region m (= #knots <= x, m=1..67) sum the active
// Q_i coefficient-wise in fp64 -> RT[spline][m-1] (float4). Regions m=0 and
// m=68 are provably zero. Main: idx = sum_j [x >= t_j] over the ORIGINAL
// unsorted knots (count is order-independent) -> 68x(v_cmp+v_addc), one LDS
// float4 gather, one 3-fma Horner. ~3x fewer VALU ops than the per-interval
// loop of rounds 2-7, and none of the readlane/bool/packed machinery whose
// cost my models kept under-estimating.
// ============================================================================

__global__ __launch_bounds__(128) void prep(const float* __restrict__ T,
                                            const float* __restrict__ C,
                                            float4* __restrict__ RT) {
    __shared__ double  td[TDIM];
    __shared__ double  cd[CDIM];
    __shared__ double  R1[QI], R2[TDIM - 2], R3[TDIM - 3];
    __shared__ double4 Qd[QI];
    __shared__ float   tf[TDIM];
    __shared__ float   srt[TDIM];

    const int s = blockIdx.x;
    const int t = threadIdx.x;

    if (t < TDIM) { float v = T[s * TDIM + t]; tf[t] = v; td[t] = (double)v; }
    if (t >= 64 && t < 64 + CDIM) cd[t - 64] = (double)C[s * CDIM + t - 64];
    __syncthreads();

    // Safe reciprocals (0/0 := 0; fp64 diff is 0 iff fp32 values equal).
    if (t < TDIM - 1) { double d = td[t + 1] - td[t]; R1[t] = (d == 0.0) ? 0.0 : 1.0 / d; }
    if (t < TDIM - 2) { double d = td[t + 2] - td[t]; R2[t] = (d == 0.0) ? 0.0 : 1.0 / d; }
    if (t < TDIM - 3) { double d = td[t + 3] - td[t]; R3[t] = (d == 0.0) ? 0.0 : 1.0 / d; }
    // Rank-sort the 68 knots (ties broken by index -> deterministic).
    if (t < TDIM) {
        float v = tf[t];
        int r = 0;
        for (int k = 0; k < TDIM; ++k)
            r += (tf[k] < v) || (tf[k] == v && k < t);
        srt[r] = v;
    }
    __syncthreads();

    // Expand Q_i: cubic for interval i as sum over <=8 Cox-de Boor lattice
    // paths (c_j index j in [i-3,i] clamped to [0,63] -> all R/td in bounds).
    if (t < QI) {
        const int i = t;
        double q0 = 0, q1 = 0, q2 = 0, q3 = 0;
        for (int j = i - 3; j <= i; ++j) {
            if (j < 0 || j > CDIM - 1) continue;
            double cj = cd[j];
            for (int b2 = 0; b2 < 2; ++b2) {
                int m2 = j + b2;
                double D3 = R3[j + b2];
                double p3 = b2 ? -D3 : D3;
                double r3 = b2 ? D3 * td[j + 4] : -D3 * td[j];
                for (int b1 = 0; b1 < 2; ++b1) {
                    int m1 = m2 + b1;
                    double D2 = R2[m2 + b1];
                    double p2 = b1 ? -D2 : D2;
                    double r2 = b1 ? D2 * td[m2 + 3] : -D2 * td[m2];
                    for (int b0 = 0; b0 < 2; ++b0) {
                        if (m1 + b0 != i) continue;   // path must end at interval i
                        double D1 = R1[m1 + b0];
                        double p1 = b0 ? -D1 : D1;
                        double r1 = b0 ? D1 * td[m1 + 2] : -D1 * td[m1];
                        double a2 = p3 * p2, a1 = p3 * r2 + r3 * p2, a0 = r3 * r2;
                        q3 += cj * (a2 * p1);
                        q2 += cj * (a2 * r1 + a1 * p1);
                        q1 += cj * (a1 * r1 + a0 * p1);
                        q0 += cj * (a0 * r1);
                    }
                }
            }
        }
        double4 q; q.x = q0; q.y = q1; q.z = q2; q.w = q3;
        Qd[i] = q;
    }
    __syncthreads();

    // Region sums: for m = t in 1..67, x* = srt[m-1] (largest knot <= any x in
    // the region); active i <=> tf[i] <= x* < tf[i+1] (same fp32 predicates as
    // the reference). Coefficient-wise fp64 sum -> one fp32 cubic per region.
    if (t >= 1 && t <= RTN) {
        const float xs = srt[t - 1];
        double a0 = 0, a1 = 0, a2 = 0, a3 = 0;
        for (int i = 0; i < QI; ++i) {
            if (tf[i] <= xs && xs < tf[i + 1]) {
                double4 q = Qd[i];
                a0 += q.x; a1 += q.y; a2 += q.z; a3 += q.w;
            }
        }
        float4 v; v.x = (float)a0; v.y = (float)a1; v.z = (float)a2; v.w = (float)a3;
        RT[s * RTN + (t - 1)] = v;
    }
}

__global__ __launch_bounds__(NTHR) void bspline_main(const float* __restrict__ X,
                                                     const float* __restrict__ T,
                                                     const float4* __restrict__ RT,
                                                     float* __restrict__ O) {
    __shared__ float4 rt[TCOLS * RTN];    // 17,152 B: region cubics for 16 splines
    __shared__ float  xl[TCOLS * PITCH];  //  8,256 B: x tile [col][row]; reused for out

    const int tid  = threadIdx.x;
    const int lane = tid & 63;
    const int w    = tid >> 6;
    const int r0   = blockIdx.x * TROWS;
    const int s0   = blockIdx.y * TCOLS;

    // Stage region tables: contiguous copy (global layout == LDS layout).
    for (int e = tid; e < TCOLS * RTN; e += NTHR)
        rt[e] = RT[s0 * RTN + e];

    // Stage X tile: coalesced global (4 full 64B lines per wave-instr);
    // LDS banks (c*129 + r) % 32 -> 2-way max within a wave (free).
    #pragma unroll
    for (int it = 0; it < TROWS * TCOLS / NTHR; ++it) {   // 8 iters
        int e = tid + it * NTHR;
        int r = e >> 4, c = e & 15;
        xl[c * PITCH + r] = X[(r0 + r) * NSPL + s0 + c];
    }
    __syncthreads();

    // Wave w owns columns 4w..4w+3 exclusively; 2 rows per lane per column.
    #pragma unroll 1
    for (int cc = 0; cc < 4; ++cc) {
        const int c  = w * 4 + cc;
        const int sp = __builtin_amdgcn_readfirstlane(s0 + c);
        const float* kn = T + sp * TDIM;     // wave-uniform -> s_load stream

        const float x0 = xl[c * PITCH + lane];         // stride-1: conflict-free
        const float x1 = xl[c * PITCH + lane + 64];
        unsigned n0 = 0, n1 = 0;
        #pragma unroll
        for (int j = 0; j < TDIM; ++j) {
            float tj = kn[j];                // uniform scalar; loop fully unrolled
            n0 += (x0 >= tj);                // v_cmp + v_addc
            n1 += (x1 >= tj);
        }
        // Region m = n (count); table entry m-1 for m in [1,67]; m=0/68 -> 0.
        const int m0 = (n0 < 1u ? 0 : (n0 > 67u ? 66 : (int)n0 - 1));
        const int m1 = (n1 < 1u ? 0 : (n1 > 67u ? 66 : (int)n1 - 1));
        float4 p0 = rt[c * RTN + m0];        // divergent ds_read_b128 gather
        float4 p1 = rt[c * RTN + m1];
        float y0 = fmaf(fmaf(fmaf(p0.w, x0, p0.z), x0, p0.y), x0, p0.x);
        float y1 = fmaf(fmaf(fmaf(p1.w, x1, p1.z), x1, p1.y), x1, p1.x);
        y0 = (n0 - 1u < 67u) ? y0 : 0.f;     // m=0 or m=68 -> outside all knots
        y1 = (n1 - 1u < 67u) ? y1 : 0.f;
        // In-place write-back: column c touched only by wave w, x reads done.
        xl[c * PITCH + lane]      = y0;
        xl[c * PITCH + lane + 64] = y1;
    }
    __syncthreads();

    // Write out: full 64B lines per row.
    #pragma unroll
    for (int it = 0; it < TROWS * TCOLS / NTHR; ++it) {
        int e = tid + it * NTHR;
        int r = e >> 4, c = e & 15;
        O[(r0 + r) * NSPL + s0 + c] = xl[c * PITCH + r];
    }
}

extern "C" void kernel_launch(void* const* d_in, const int* in_sizes, int n_in,
                              void* d_out, int out_size, void* d_ws, size_t ws_size,
                              hipStream_t stream) {
    const float* X = (const float*)d_in[0];  // [65536, 64]
    const float* T = (const float*)d_in[1];  // [64, 68]
    const float* C = (const float*)d_in[2];  // [64, 64]
    float* O = (float*)d_out;                // [65536, 64]
    float4* RT = (float4*)d_ws;              // 64*67 float4 = 68,608 B (== R2-proven ws use)

    prep<<<NSPL, 128, 0, stream>>>(T, C, RT);
    dim3 grid(BATCH / TROWS, NSPL / TCOLS);  // (512, 4) = 2048 blocks, ~6/CU resident
    bspline_main<<<grid, NTHR, 0, stream>>>(X, T, RT, O);
}